// Round 12
// baseline (153.805 us; speedup 1.0000x reference)
//
#include <hip/hip_runtime.h>
#include <math.h>

#define BB  8
#define HH  512
#define WW  512
#define HW  (HH*WW)

#define TSX 32
#define TSY 32
#define GR  34           // guidance tile (halo 1)
#define GS2 36           // packed guidance row stride (u32 words)
#define FBWORDS (GR*GS2) // 1224 (fb plane; w plane follows)
#define WB  FBWORDS
#define FR  36           // flow tile (halo 2)
#define FPD 37           // fpd row stride (float2 elems)
#define PLN (FR*FPD)

#define WS_GOFF 32768                     // FB plane offset in d_ws
#define WS_WOFF (WS_GOFF + BB*HW*4)       // W plane
#define NREC 24                           // uint4 per lane record

typedef __attribute__((ext_vector_type(8)))  short short8;
typedef __attribute__((ext_vector_type(4)))  float float4v;
typedef __attribute__((ext_vector_type(16))) float float16v;
typedef __attribute__((ext_vector_type(2)))  float float2v;
typedef __attribute__((ext_vector_type(4)))  int   int4v;
typedef __attribute__((ext_vector_type(4)))  uint  uint4v;

#define MFMA32(a,b,c) __builtin_amdgcn_mfma_f32_32x32x16_bf16((a),(b),(c),0,0,0)

template <typename T>
static __device__ __forceinline__ void keep(T& x) { asm volatile("" : "+v"(x)); }

static __device__ __forceinline__ uint  fu(float f) { return __float_as_uint(f); }
static __device__ __forceinline__ float uf(uint u)  { return __uint_as_float(u); }

static __device__ __forceinline__ ushort f2bf_rne(float f) {
    uint u = fu(f);
    u += 0x7fffu + ((u >> 16) & 1u);
    return (ushort)(u >> 16);
}
static __device__ __forceinline__ void split_rne(float f, ushort& hi, ushort& lo) {
    hi = f2bf_rne(f);
    float r = f - uf((uint)hi << 16);
    lo = f2bf_rne(r);
}

// conv1 K-slot -> original k (27 = ic*9 + tap; ic: 0=fb0,1=fb1,2=w); -1 = dead
static __device__ __forceinline__ int slot_k1(int chunk, int h5, int i) {
    const int w = i >> 1, e = i & 1;
    if (chunk == 0) return 9 * e + 4 * h5 + w;          // fb words, taps 0..7
    if (h5 == 0) return (w == 0) ? (9 * e + 8)          // fb word tap 8
                                 : (18 + 3 * (w - 1) + e); // w pairs (0,1)(3,4)(6,7)
    if (w == 3 || e == 1) return -1;                     // dead
    return 20 + 3 * w;                                   // w taps 2,5,8
}

// conv2 output-row tap map: tile T, reg r -> tap kk (channel handled separately)
static __device__ __forceinline__ int tap_T(int T, int r) {
    if (T == 0) return 5 * (r >> 2) + (r & 3);   // taps (0..3, 0..3)
    if (r < 4)  return 20 + r;                   // taps (4, 0..3)
    if (r < 8)  return 5 * (r & 3) + 4;          // taps (0..3, 4)
    if (r == 8) return 24;                       // tap  (4, 4)
    return -1;
}

// ===================== setup: per-lane records -> ws =====================
// rec layout (uint4 idx): 0..1 a1h[chunk]; 2..3 a1l[chunk];
// 4..7 a2[T][chunk]; 8..11 bi1 (f32x16); 12..15 bi2 T0; 16..19 bi2 T1;
// 20..21 off1 (8 word-offsets into g32)
__global__ __launch_bounds__(64)
void setup_params(const float* __restrict__ w1, const float* __restrict__ b1,
                  const float* __restrict__ w2, const float* __restrict__ b2,
                  uint4v* __restrict__ ws)
{
    const int L = threadIdx.x;
    const int c5 = L & 31, h5 = L >> 5;
    uint4v* rec = ws + (size_t)L * NREC;

    // conv1 A: row(oc)=c5, k-slot = 8*h5+i per chunk
    #pragma unroll
    for (int chunk = 0; chunk < 2; ++chunk) {
        short8 hi8, lo8;
        #pragma unroll
        for (int i = 0; i < 8; ++i) {
            const int k = slot_k1(chunk, h5, i);
            const float f = (k >= 0) ? w1[c5 * 27 + k] : 0.f;
            ushort h_, l_; split_rne(f, h_, l_);
            hi8[i] = (short)h_; lo8[i] = (short)l_;
        }
        *reinterpret_cast<short8*>(&rec[0 + chunk]) = hi8;
        *reinterpret_cast<short8*>(&rec[2 + chunk]) = lo8;
    }
    // conv2 A: global row R = 32T + c5 -> (chR, kk); k-slot s=8h5+i -> oc
    #pragma unroll
    for (int T = 0; T < 2; ++T) {
        const int j   = c5;
        const int chR = (j >> 2) & 1;
        const int jjR = j - 4 * chR;
        const int rR  = (jjR & 3) + 4 * (jjR >> 3);
        const int kk  = tap_T(T, rR);
        #pragma unroll
        for (int chunk = 0; chunk < 2; ++chunk) {
            short8 a8;
            #pragma unroll
            for (int i = 0; i < 8; ++i) {
                const int oc = (i & 3) + 8 * (i >> 2) + 4 * h5 + 16 * chunk;
                const float f = (kk >= 0) ? w2[(25 * chR + kk) * 32 + oc] : 0.f;
                a8[i] = (short)f2bf_rne(f);
            }
            *reinterpret_cast<short8*>(&rec[4 + T * 2 + chunk]) = a8;
        }
    }
    // bi1: reg r -> oc row = (r&3)+8*(r>>2)+4*h5
    #pragma unroll
    for (int p = 0; p < 4; ++p) {
        float4v v;
        #pragma unroll
        for (int e = 0; e < 4; ++e) {
            const int r = 4 * p + e;
            v[e] = b1[(r & 3) + 8 * (r >> 2) + 4 * h5];
        }
        *reinterpret_cast<float4v*>(&rec[8 + p]) = v;
    }
    // bi2[T]: reg r -> tap; channel = h5
    #pragma unroll
    for (int T = 0; T < 2; ++T) {
        #pragma unroll
        for (int p = 0; p < 4; ++p) {
            float4v v;
            #pragma unroll
            for (int e = 0; e < 4; ++e) {
                const int kk = tap_T(T, 4 * p + e);
                v[e] = (kk >= 0) ? b2[25 * h5 + kk] : 0.f;
            }
            *reinterpret_cast<float4v*>(&rec[12 + 4 * T + p]) = v;
        }
    }
    // off1: 8 word offsets (chunk*4 + w)
    {
        int4v o0, o1;
        #pragma unroll
        for (int w = 0; w < 4; ++w) {
            const int t = 4 * h5 + w;
            o0[w] = (t / 3) * GS2 + (t % 3);                       // chunk0: fb words
            if (h5 == 0) o1[w] = (w == 0) ? (2 * GS2 + 2)          // fb tap 8
                                          : (WB + (w - 1) * GS2);  // w pairs col 0
            else         o1[w] = (w < 3) ? (WB + w * GS2 + 2)      // w col 2 words
                                         : WB;                     // dead
        }
        *reinterpret_cast<int4v*>(&rec[20]) = o0;
        *reinterpret_cast<int4v*>(&rec[21]) = o1;
    }
}

// ========== K1: guidance, 2 px/thread STRIDED (coalesced, 2x ILP) ==========
__global__ __launch_bounds__(256)
void guidance_kernel(const float* __restrict__ v0,
                     const float* __restrict__ v2,
                     uint* __restrict__ GFB, ushort* __restrict__ GW)
{
    const int bid = blockIdx.x;          // one image row per block
    const int y = bid & (HH - 1);
    const int b = bid >> 9;
    const int tid = threadIdx.x;

    const float* v0b = v0 + (size_t)b * 2 * HW;
    const float* v2b = v2 + (size_t)b * 2 * HW;

    #pragma unroll
    for (int half = 0; half < 2; ++half) {
        const int x = tid + half * 256;
        const float f0 = v0b[y * WW + x];
        const float f1 = v0b[HW + y * WW + x];

        const float sgx = (-1.0f + x * (2.0f / (WW - 1))) + f0 * (2.0f / WW);
        const float sgy = (-1.0f + y * (2.0f / (HH - 1))) + f1 * (2.0f / HH);
        const float ixf = (sgx + 1.0f) * (0.5f * (WW - 1));
        const float iyf = (sgy + 1.0f) * (0.5f * (HH - 1));
        const float x0f = floorf(ixf), y0f = floorf(iyf);
        const int   x0  = (int)x0f,   y0i = (int)y0f;
        const float wx1 = ixf - x0f, wx0 = 1.0f - wx1;
        const float wy1 = iyf - y0f, wy0 = 1.0f - wy1;
        float s0 = 0.f, s1 = 0.f;
        #pragma unroll
        for (int cy = 0; cy < 2; ++cy) {
            const int yc = y0i + cy;
            const float wy = cy ? wy1 : wy0;
            if (yc >= 0 && yc < HH) {
                #pragma unroll
                for (int cx = 0; cx < 2; ++cx) {
                    const int xc = x0 + cx;
                    if (xc >= 0 && xc < WW) {
                        const float wgt = wy * (cx ? wx1 : wx0);
                        const int i2 = yc * WW + xc;
                        s0 = fmaf(wgt, v2b[i2], s0);
                        s1 = fmaf(wgt, v2b[HW + i2], s1);
                    }
                }
            }
        }
        const float fb0 = f0 + s0;
        const float fb1 = f1 + s1;
        const float wv  = __expf(-sqrtf(fmaf(fb0, fb0, fb1 * fb1)));

        const size_t base = (size_t)b * HW + y * WW + x;
        GFB[base] = (uint)f2bf_rne(fb0) | ((uint)f2bf_rne(fb1) << 16);
        GW[base]  = f2bf_rne(wv);
    }
}

// ====== K2: 32x32 MFMA, channel = h5, no shuffles, no divergence ======
__global__ __launch_bounds__(256, 3)
void refine_kernel(const float* __restrict__ v0,
                   const uint* __restrict__ GFB,
                   const ushort* __restrict__ GW,
                   const uint4v* __restrict__ P,
                   float* __restrict__ out)
{
    __shared__ uint    g32[2 * FBWORDS];     // fb-pair plane | w-pair plane
    __shared__ float2v fpd[2 * PLN];         // per-channel dup-pair flow planes

    const int bx0 = blockIdx.x * TSX;
    const int by0 = blockIdx.y * TSY;
    const int b   = blockIdx.z;
    const int tid = threadIdx.x;
    const int w   = tid >> 6;
    const int L   = tid & 63;
    const int c5  = L & 31;
    const int h5  = L >> 5;

    const float*  v0b  = v0 + (size_t)b * 2 * HW;
    const uint*   GFBb = GFB + (size_t)b * HW;
    const ushort* GWb  = GW + (size_t)b * HW;
    const uint4v* rec  = P + (size_t)L * NREC;

    // ---- per-lane params ----
    short8 a1h0 = *reinterpret_cast<const short8*>(&rec[0]); keep(a1h0);
    short8 a1h1 = *reinterpret_cast<const short8*>(&rec[1]); keep(a1h1);
    short8 a1l0 = *reinterpret_cast<const short8*>(&rec[2]); keep(a1l0);
    short8 a1l1 = *reinterpret_cast<const short8*>(&rec[3]); keep(a1l1);
    short8 a2_00 = *reinterpret_cast<const short8*>(&rec[4]); keep(a2_00);
    short8 a2_01 = *reinterpret_cast<const short8*>(&rec[5]); keep(a2_01);
    short8 a2_10 = *reinterpret_cast<const short8*>(&rec[6]); keep(a2_10);
    short8 a2_11 = *reinterpret_cast<const short8*>(&rec[7]); keep(a2_11);
    const float16v bi1   = *reinterpret_cast<const float16v*>(&rec[8]);
    const float16v bi2_0 = *reinterpret_cast<const float16v*>(&rec[12]);
    const float16v bi2_1 = *reinterpret_cast<const float16v*>(&rec[16]);
    int off1[8];
    {
        const int4v o0 = *reinterpret_cast<const int4v*>(&rec[20]);
        const int4v o1 = *reinterpret_cast<const int4v*>(&rec[21]);
        #pragma unroll
        for (int j = 0; j < 4; ++j) { off1[j] = o0[j]; off1[4 + j] = o1[j]; }
    }

    // ---- stage flow: dup-pair (f[x], f[x+1]) per channel, f32 ----
    for (int i = tid; i < FR * FR; i += 256) {
        const int ly = i / FR, lx = i - (i / FR) * FR;
        const int y = by0 - 2 + ly, x = bx0 - 2 + lx;
        float a0 = 0.f, a1 = 0.f, b0 = 0.f, b1v = 0.f;
        if ((unsigned)y < HH) {
            const int row = y * WW;
            if ((unsigned)x < WW)       { a0 = v0b[row + x];      a1 = v0b[HW + row + x]; }
            if ((unsigned)(x + 1) < WW) { b0 = v0b[row + x + 1];  b1v = v0b[HW + row + x + 1]; }
        }
        float2v p0; p0[0] = a0; p0[1] = b0;
        float2v p1; p1[0] = a1; p1[1] = b1v;
        fpd[ly * FPD + lx]       = p0;
        fpd[PLN + ly * FPD + lx] = p1;
    }
    // ---- stage packed guidance: fb words + w pair-words ----
    for (int i = tid; i < GR * GR; i += 256) {
        const int r = i / GR, cc = i - (i / GR) * GR;
        const int y = by0 - 1 + r;
        const int xl = bx0 - 1 + cc;
        uint fbw = 0u, wl = 0u, wr = 0u;
        if ((unsigned)y < HH) {
            const size_t row = (size_t)y * WW;
            if ((unsigned)xl < WW) {
                fbw = GFBb[row + xl];
                wl  = GWb[row + xl];
            }
            const int xr = xl + 1;
            if ((unsigned)xr < WW) wr = GWb[row + xr];
        }
        g32[r * GS2 + cc]      = fbw;
        g32[WB + r * GS2 + cc] = wl | (wr << 16);
    }
    __syncthreads();

    const float2v* pl = fpd + h5 * PLN;

    // ---- 8 groups of 32 px per wave (one tile row each) ----
    for (int gr = 0; gr < 8; ++gr) {
        const int py = 8 * w + gr;
        const int gb = py * GS2 + c5;

        // B1: 8 word gathers -> 2 K-chunk fragments
        uint4v uA, uB;
        uA[0] = g32[off1[0] + gb]; uA[1] = g32[off1[1] + gb];
        uA[2] = g32[off1[2] + gb]; uA[3] = g32[off1[3] + gb];
        uB[0] = g32[off1[4] + gb]; uB[1] = g32[off1[5] + gb];
        uB[2] = g32[off1[6] + gb]; uB[3] = g32[off1[7] + gb];
        const short8 b1c0 = *reinterpret_cast<const short8*>(&uA);
        const short8 b1c1 = *reinterpret_cast<const short8*>(&uB);

        // conv3x3: 32x32x16 x (2 chunks x hi/lo), bias in C
        float16v acc1 = bi1;
        acc1 = MFMA32(a1l0, b1c0, acc1);
        acc1 = MFMA32(a1h0, b1c0, acc1);
        acc1 = MFMA32(a1l1, b1c1, acc1);
        acc1 = MFMA32(a1h1, b1c1, acc1);

        // ReLU + trunc-bf16 -> conv2 B frags directly from acc regs
        short8 b2c0, b2c1;
        #pragma unroll
        for (int r = 0; r < 8; ++r) {
            b2c0[r] = (short)(fu(fmaxf(acc1[r], 0.f)) >> 16);
            b2c1[r] = (short)(fu(fmaxf(acc1[8 + r], 0.f)) >> 16);
        }

        // conv1x1: 2 row-tiles x 2 K-chunks, bias in C
        float16v acc2a = bi2_0, acc2b = bi2_1;
        acc2a = MFMA32(a2_00, b2c0, acc2a);
        acc2a = MFMA32(a2_01, b2c1, acc2a);
        acc2b = MFMA32(a2_10, b2c0, acc2b);
        acc2b = MFMA32(a2_11, b2c1, acc2b);

        // combine: lane owns channel h5 entirely; 15 ds_read_b64, 25 fma
        const int rb = py * FPD + c5;
        float s0 = 0.f, s1 = 0.f, s2 = 0.f, s3 = 0.f;
        #pragma unroll
        for (int ky = 0; ky < 4; ++ky) {
            const float2v dA = pl[rb + ky * FPD];       // taps (ky,0),(ky,1)
            const float2v dB = pl[rb + ky * FPD + 2];   // taps (ky,2),(ky,3)
            const float2v dC = pl[rb + ky * FPD + 4];   // tap  (ky,4) in elem0
            s0 = fmaf(acc2a[4 * ky + 0], dA[0], s0);
            s1 = fmaf(acc2a[4 * ky + 1], dA[1], s1);
            s2 = fmaf(acc2a[4 * ky + 2], dB[0], s2);
            s3 = fmaf(acc2a[4 * ky + 3], dB[1], s3);
            s0 = fmaf(acc2b[4 + ky],     dC[0], s0);
        }
        {
            const float2v dA = pl[rb + 4 * FPD];        // taps (4,0),(4,1)
            const float2v dB = pl[rb + 4 * FPD + 2];    // taps (4,2),(4,3)
            const float2v dC = pl[rb + 4 * FPD + 4];    // tap  (4,4) in elem0
            s1 = fmaf(acc2b[0], dA[0], s1);
            s2 = fmaf(acc2b[1], dA[1], s2);
            s3 = fmaf(acc2b[2], dB[0], s3);
            s0 = fmaf(acc2b[3], dB[1], s0);
            s1 = fmaf(acc2b[8], dC[0], s1);
        }
        const float s = (s0 + s1) + (s2 + s3);

        out[((size_t)b * 2 + h5) * HW + (size_t)(by0 + py) * WW + bx0 + c5] = s;
    }
}

extern "C" void kernel_launch(void* const* d_in, const int* in_sizes, int n_in,
                              void* d_out, int out_size, void* d_ws, size_t ws_size,
                              hipStream_t stream) {
    const float* v0 = (const float*)d_in[0];
    const float* v2 = (const float*)d_in[1];
    const float* w1 = (const float*)d_in[2];
    const float* b1 = (const float*)d_in[3];
    const float* w2 = (const float*)d_in[4];
    const float* b2 = (const float*)d_in[5];
    uint4v* ws  = (uint4v*)d_ws;
    uint*   GFB = (uint*)((char*)d_ws + WS_GOFF);
    ushort* GW  = (ushort*)((char*)d_ws + WS_WOFF);

    setup_params<<<1, 64, 0, stream>>>(w1, b1, w2, b2, ws);
    guidance_kernel<<<BB * HH, 256, 0, stream>>>(v0, v2, GFB, GW);

    dim3 grid(WW / TSX, HH / TSY, BB);
    refine_kernel<<<grid, dim3(256, 1, 1), 0, stream>>>(v0, GFB, GW, ws, (float*)d_out);
}

// Round 13
// 66.636 us; speedup vs baseline: 2.3082x; 2.3082x over previous
//
#include <hip/hip_runtime.h>
#include <math.h>

#define BB  8
#define HH  512
#define WW  512
#define HW  (HH*WW)

#define TSX 32           // tile width
#define TSY 32           // tile height
#define GR  34           // guidance tile (halo 1)
#define GS2 36           // packed guidance row stride (u32 words)
#define FBWORDS (GR*GS2) // fb-plane words (w-plane follows)
#define FR  36           // flow tile (halo 2)
#define FPS2 37          // flow row stride (float2 units)

#define WS_GOFF 32768                     // FB plane (u32[B*HW]) offset in d_ws
#define WS_WOFF (WS_GOFF + BB*HW*4)       // W plane (u16[B*HW])

typedef __attribute__((ext_vector_type(8))) short  short8;
typedef __attribute__((ext_vector_type(4))) float  float4v;
typedef __attribute__((ext_vector_type(2))) float  float2v;
typedef __attribute__((ext_vector_type(4))) int    int4v;
typedef __attribute__((ext_vector_type(4))) uint   uint4v;

#define MFMA16x32(a,b,c) __builtin_amdgcn_mfma_f32_16x16x32_bf16((a),(b),(c),0,0,0)

// launder: force materialization (anti-remat)
template <typename T>
static __device__ __forceinline__ void keep(T& x) { asm volatile("" : "+v"(x)); }

static __device__ __forceinline__ uint  fu(float f) { return __float_as_uint(f); }
static __device__ __forceinline__ float uf(uint u)  { return __uint_as_float(u); }

static __device__ __forceinline__ ushort f2bf_rne(float f) {
    uint u = fu(f);
    u += 0x7fffu + ((u >> 16) & 1u);
    return (ushort)(u >> 16);
}
static __device__ __forceinline__ void split_rne(float f, ushort& hi, ushort& lo) {
    hi = f2bf_rne(f);
    float r = f - uf((uint)hi << 16);
    lo = f2bf_rne(r);
}

// conv2 row-permutation tap (verified r7-r11)
static __device__ __forceinline__ int tap_kk(int mtodd, int qr, int rr) {
    if (!mtodd) return 5 * qr + rr;
    if (rr == 0) return 5 * qr + 4;
    if (rr == 1) return 20 + qr;
    if (rr == 2 && qr == 3) return 24;
    return -1;
}

// conv1 K-slot -> original k (pair-packed scheme, verified r10-r11)
static __device__ __forceinline__ int slot_k(int q, int i) {
    const int p = 4 * q + (i >> 1), e = i & 1;
    if (p <= 8)  return e ? 9 + p : p;
    if (p <= 11) return 18 + 3 * (p - 9) + e;
    if (p <= 14) return e ? -1 : 18 + 3 * (p - 12) + 2;
    return -1;
}

// ============== setup (device fn; run by K1 block 0, lanes 0..63) ==============
// chunks (uint4 ws[chunk*64 + lane]):
//  0..1 a1h[t]  2..3 a1l[t]   conv1 A, slot-mapped per slot_k, split hi/lo
//  4..7 a2[mt]                conv2 A (K-permuted oc), RNE bf16
// 12..13 bi1[t]  14..17 bi2[mt]
// 18 off1 int4               4 word-offsets into g32 (fb plane | w plane)
static __device__ void setup_lane(const float* __restrict__ w1, const float* __restrict__ b1,
                                  const float* __restrict__ w2, const float* __restrict__ b2,
                                  uint4v* __restrict__ ws, int L)
{
    const int c = L & 15, q = L >> 4;

    #pragma unroll
    for (int t = 0; t < 2; ++t) {
        short8 hi8, lo8;
        #pragma unroll
        for (int i = 0; i < 8; ++i) {
            const int k = slot_k(q, i);
            const float f = (k >= 0) ? w1[(16 * t + c) * 27 + k] : 0.f;
            ushort h_, l_; split_rne(f, h_, l_);
            hi8[i] = (short)h_; lo8[i] = (short)l_;
        }
        *reinterpret_cast<short8*>(&ws[(0 + t) * 64 + L]) = hi8;
        *reinterpret_cast<short8*>(&ws[(2 + t) * 64 + L]) = lo8;
    }
    #pragma unroll
    for (int mt = 0; mt < 4; ++mt) {
        const int ch = mt >> 1;
        const int kk = tap_kk(mt & 1, c >> 2, c & 3);
        short8 a8;
        #pragma unroll
        for (int i = 0; i < 8; ++i) {
            const int oc = (i < 4) ? (4 * q + i) : (16 + 4 * q + (i - 4));
            const float f = (kk >= 0) ? w2[(25 * ch + kk) * 32 + oc] : 0.f;
            a8[i] = (short)f2bf_rne(f);
        }
        *reinterpret_cast<short8*>(&ws[(4 + mt) * 64 + L]) = a8;
    }
    #pragma unroll
    for (int t = 0; t < 2; ++t) {
        float4v v;
        #pragma unroll
        for (int r = 0; r < 4; ++r) v[r] = b1[16 * t + 4 * q + r];
        *reinterpret_cast<float4v*>(&ws[(12 + t) * 64 + L]) = v;
    }
    #pragma unroll
    for (int mt = 0; mt < 4; ++mt) {
        const int ch = mt >> 1;
        float4v v;
        #pragma unroll
        for (int r = 0; r < 4; ++r) {
            const int kk = tap_kk(mt & 1, q, r);
            v[r] = (kk >= 0) ? b2[25 * ch + kk] : 0.f;
        }
        *reinterpret_cast<float4v*>(&ws[(14 + mt) * 64 + L]) = v;
    }
    {
        int4v o;
        #pragma unroll
        for (int pl = 0; pl < 4; ++pl) {
            const int p = 4 * q + pl;
            int off;
            if (p <= 8)       off = (p / 3) * GS2 + (p % 3);        // FB word
            else if (p <= 11) off = FBWORDS + (p - 9) * GS2;        // W (ky,0)
            else if (p <= 14) off = FBWORDS + (p - 12) * GS2 + 2;   // W (ky,2)
            else              off = FBWORDS;                        // pad (dead)
            o[pl] = off;
        }
        *reinterpret_cast<int4v*>(&ws[18 * 64 + L]) = o;
    }
}

// ====== K1: guidance, 2 px/thread STRIDED (coalesced) + folded setup ======
__global__ __launch_bounds__(256)
void guidance_kernel(const float* __restrict__ v0,
                     const float* __restrict__ v2,
                     const float* __restrict__ w1, const float* __restrict__ b1,
                     const float* __restrict__ w2, const float* __restrict__ b2,
                     uint* __restrict__ GFB, ushort* __restrict__ GW,
                     uint4v* __restrict__ ws)
{
    if (blockIdx.x == 0 && threadIdx.x < 64)
        setup_lane(w1, b1, w2, b2, ws, threadIdx.x);

    const int bid = blockIdx.x;          // one image row per block
    const int y = bid & (HH - 1);
    const int b = bid >> 9;
    const int tid = threadIdx.x;

    const float* v0b = v0 + (size_t)b * 2 * HW;
    const float* v2b = v2 + (size_t)b * 2 * HW;

    #pragma unroll
    for (int half = 0; half < 2; ++half) {
        const int x = tid + half * 256;
        const float f0 = v0b[y * WW + x];
        const float f1 = v0b[HW + y * WW + x];

        const float sgx = (-1.0f + x * (2.0f / (WW - 1))) + f0 * (2.0f / WW);
        const float sgy = (-1.0f + y * (2.0f / (HH - 1))) + f1 * (2.0f / HH);
        const float ixf = (sgx + 1.0f) * (0.5f * (WW - 1));
        const float iyf = (sgy + 1.0f) * (0.5f * (HH - 1));
        const float x0f = floorf(ixf), y0f = floorf(iyf);
        const int   x0  = (int)x0f,   y0i = (int)y0f;
        const float wx1 = ixf - x0f, wx0 = 1.0f - wx1;
        const float wy1 = iyf - y0f, wy0 = 1.0f - wy1;
        float s0 = 0.f, s1 = 0.f;
        #pragma unroll
        for (int cy = 0; cy < 2; ++cy) {
            const int yc = y0i + cy;
            const float wy = cy ? wy1 : wy0;
            if (yc >= 0 && yc < HH) {
                #pragma unroll
                for (int cx = 0; cx < 2; ++cx) {
                    const int xc = x0 + cx;
                    if (xc >= 0 && xc < WW) {
                        const float wgt = wy * (cx ? wx1 : wx0);
                        const int i2 = yc * WW + xc;
                        s0 = fmaf(wgt, v2b[i2], s0);
                        s1 = fmaf(wgt, v2b[HW + i2], s1);
                    }
                }
            }
        }
        const float fb0 = f0 + s0;
        const float fb1 = f1 + s1;
        const float wv  = __expf(-sqrtf(fmaf(fb0, fb0, fb1 * fb1)));

        const size_t base = (size_t)b * HW + y * WW + x;
        GFB[base] = (uint)f2bf_rne(fb0) | ((uint)f2bf_rne(fb1) << 16);
        GW[base]  = f2bf_rne(wv);
    }
}

// ====== K2: convs + combine (r11 structure, unroll 4) ======
__global__ __launch_bounds__(256, 3)
void refine_kernel(const float* __restrict__ v0,
                   const uint* __restrict__ GFB,
                   const ushort* __restrict__ GW,
                   const uint4v* __restrict__ P,
                   float* __restrict__ out)
{
    __shared__ uint    g32[2 * FBWORDS];          // fb-pair plane | w-pair plane
    __shared__ float2v f2[FR * FPS2];             // flow tile, channels interleaved

    const int bx0 = blockIdx.x * TSX;
    const int by0 = blockIdx.y * TSY;
    const int b   = blockIdx.z;
    const int tid = threadIdx.x;
    const int w   = tid >> 6;
    const int L   = tid & 63;
    const int c   = L & 15;
    const int q   = L >> 4;

    const float*  v0b  = v0 + (size_t)b * 2 * HW;
    const uint*   GFBb = GFB + (size_t)b * HW;
    const ushort* GWb  = GW + (size_t)b * HW;

    // ---- per-lane params (loaded once) ----
    short8 a1h[2], a1l[2], a2[4];
    #pragma unroll
    for (int t = 0; t < 2; ++t) {
        a1h[t] = *reinterpret_cast<const short8*>(&P[(0 + t) * 64 + L]); keep(a1h[t]);
        a1l[t] = *reinterpret_cast<const short8*>(&P[(2 + t) * 64 + L]); keep(a1l[t]);
    }
    #pragma unroll
    for (int mt = 0; mt < 4; ++mt) {
        a2[mt] = *reinterpret_cast<const short8*>(&P[(4 + mt) * 64 + L]); keep(a2[mt]);
    }
    float4v bi1[2], bi2[4];
    #pragma unroll
    for (int t = 0; t < 2; ++t) {
        bi1[t] = *reinterpret_cast<const float4v*>(&P[(12 + t) * 64 + L]); keep(bi1[t]);
    }
    #pragma unroll
    for (int mt = 0; mt < 4; ++mt) {
        bi2[mt] = *reinterpret_cast<const float4v*>(&P[(14 + mt) * 64 + L]); keep(bi2[mt]);
    }
    int off1[4];
    {
        int4v o = *reinterpret_cast<const int4v*>(&P[18 * 64 + L]); keep(o);
        #pragma unroll
        for (int pl = 0; pl < 4; ++pl) off1[pl] = o[pl];
    }

    // ---- stage flow tile (36x36, halo 2), channels interleaved ----
    for (int i = tid; i < FR * FR; i += 256) {
        const int ly = i / FR, lx = i - (i / FR) * FR;
        const int y = by0 - 2 + ly, x = bx0 - 2 + lx;
        float f0 = 0.f, f1 = 0.f;
        if ((unsigned)y < HH && (unsigned)x < WW) {
            f0 = v0b[y * WW + x];
            f1 = v0b[HW + y * WW + x];
        }
        float2v p; p[0] = f0; p[1] = f1;
        f2[ly * FPS2 + lx] = p;
    }
    // ---- stage packed guidance: fb words + w pair-words ----
    for (int i = tid; i < GR * GR; i += 256) {
        const int r = i / GR, cc = i - (i / GR) * GR;
        const int y = by0 - 1 + r;
        const int xl = bx0 - 1 + cc;
        uint fbw = 0u, wl = 0u, wr = 0u;
        if ((unsigned)y < HH) {
            const size_t row = (size_t)y * WW;
            if ((unsigned)xl < WW) {
                fbw = GFBb[row + xl];
                wl  = GWb[row + xl];
            }
            const int xr = xl + 1;
            if ((unsigned)xr < WW) wr = GWb[row + xr];
        }
        g32[r * GS2 + cc]           = fbw;
        g32[FBWORDS + r * GS2 + cc] = wl | (wr << 16);
    }
    __syncthreads();

    // ---- 16 groups of 16 px per wave ----
    #pragma unroll 4
    for (int g = 0; g < 16; ++g) {
        const int py = 8 * w + (g >> 1);
        const int px = 16 * (g & 1) + c;
        const int gb = py * GS2 + px;

        // B1 frag: 4 u32 word gathers -> short8
        uint4v uw;
        #pragma unroll
        for (int pl = 0; pl < 4; ++pl) uw[pl] = g32[off1[pl] + gb];
        const short8 b1 = *reinterpret_cast<const short8*>(&uw);

        // conv3x3 GEMM (bf16 B, split A), bias in C
        float4v acc1_0 = bi1[0], acc1_1 = bi1[1];
        acc1_0 = MFMA16x32(a1l[0], b1, acc1_0);
        acc1_0 = MFMA16x32(a1h[0], b1, acc1_0);
        acc1_1 = MFMA16x32(a1l[1], b1, acc1_1);
        acc1_1 = MFMA16x32(a1h[1], b1, acc1_1);

        // ReLU + truncation bf16 (hi only; headroom verified) -> conv2 B frag
        short8 b2h;
        #pragma unroll
        for (int r = 0; r < 4; ++r) {
            const float h0 = fmaxf(acc1_0[r], 0.f);
            const float h1 = fmaxf(acc1_1[r], 0.f);
            b2h[r]     = (short)(fu(h0) >> 16);
            b2h[4 + r] = (short)(fu(h1) >> 16);
        }

        // conv1x1 GEMM via K-permuted 16x16x32, hi term only (4 MFMA)
        float4v acc2[4] = {bi2[0], bi2[1], bi2[2], bi2[3]};
        #pragma unroll
        for (int mt = 0; mt < 4; ++mt)
            acc2[mt] = MFMA16x32(a2[mt], b2h, acc2[mt]);

        // combine: 7 x ds_read_b64 (both channels per read)
        const int pyb   = py * FPS2 + px;
        const int base0 = pyb + q * FPS2;         // taps (q, 0..4)
        const int b4    = pyb + 4 * FPS2 + q;     // tap  (4, q)

        const float2v p0 = f2[base0];
        const float2v p1 = f2[base0 + 1];
        const float2v p2 = f2[base0 + 2];
        const float2v p3 = f2[base0 + 3];
        const float2v p4 = f2[base0 + 4];
        const float2v pb = f2[b4];
        const float2v pc = f2[base0 + 41];        // (4,4): kern==0 unless q==3

        float s0 = 0.f, s1 = 0.f;
        s0 = fmaf(acc2[0][0], p0[0], s0);  s1 = fmaf(acc2[2][0], p0[1], s1);
        s0 = fmaf(acc2[0][1], p1[0], s0);  s1 = fmaf(acc2[2][1], p1[1], s1);
        s0 = fmaf(acc2[0][2], p2[0], s0);  s1 = fmaf(acc2[2][2], p2[1], s1);
        s0 = fmaf(acc2[0][3], p3[0], s0);  s1 = fmaf(acc2[2][3], p3[1], s1);
        s0 = fmaf(acc2[1][0], p4[0], s0);  s1 = fmaf(acc2[3][0], p4[1], s1);
        s0 = fmaf(acc2[1][1], pb[0], s0);  s1 = fmaf(acc2[3][1], pb[1], s1);
        s0 = fmaf(acc2[1][2], pc[0], s0);  s1 = fmaf(acc2[3][2], pc[1], s1);

        s0 += __shfl_xor(s0, 16);
        s0 += __shfl_xor(s0, 32);
        s1 += __shfl_xor(s1, 16);
        s1 += __shfl_xor(s1, 32);

        if (q == 0) {
            const int y = by0 + py, x = bx0 + px;
            out[((size_t)b * 2 + 0) * HW + y * WW + x] = s0;
            out[((size_t)b * 2 + 1) * HW + y * WW + x] = s1;
        }
    }
}

extern "C" void kernel_launch(void* const* d_in, const int* in_sizes, int n_in,
                              void* d_out, int out_size, void* d_ws, size_t ws_size,
                              hipStream_t stream) {
    const float* v0 = (const float*)d_in[0];
    const float* v2 = (const float*)d_in[1];
    const float* w1 = (const float*)d_in[2];
    const float* b1 = (const float*)d_in[3];
    const float* w2 = (const float*)d_in[4];
    const float* b2 = (const float*)d_in[5];
    uint4v* ws  = (uint4v*)d_ws;
    uint*   GFB = (uint*)((char*)d_ws + WS_GOFF);
    ushort* GW  = (ushort*)((char*)d_ws + WS_WOFF);

    guidance_kernel<<<BB * HH, 256, 0, stream>>>(v0, v2, w1, b1, w2, b2, GFB, GW, ws);

    dim3 grid(WW / TSX, HH / TSY, BB);
    refine_kernel<<<grid, dim3(256, 1, 1), 0, stream>>>(v0, GFB, GW, ws, (float*)d_out);
}

// Round 14
// 62.993 us; speedup vs baseline: 2.4416x; 1.0578x over previous
//
#include <hip/hip_runtime.h>
#include <math.h>

#define BB  8
#define HH  512
#define WW  512
#define HW  (HH*WW)

#define TSX 32           // tile width
#define TSY 32           // tile height
#define GR  34           // guidance tile (halo 1)
#define GS2 36           // packed guidance row stride (u32 words)
#define FBWORDS (GR*GS2) // fb-plane words (w-plane follows)
#define FR  36           // flow tile (halo 2)
#define FPS2 37          // flow row stride (float2 units)

typedef __attribute__((ext_vector_type(8))) short  short8;
typedef __attribute__((ext_vector_type(4))) float  float4v;
typedef __attribute__((ext_vector_type(2))) float  float2v;
typedef __attribute__((ext_vector_type(4))) int    int4v;
typedef __attribute__((ext_vector_type(4))) uint   uint4v;

#define MFMA16x32(a,b,c) __builtin_amdgcn_mfma_f32_16x16x32_bf16((a),(b),(c),0,0,0)

// launder: force materialization (anti-remat)
template <typename T>
static __device__ __forceinline__ void keep(T& x) { asm volatile("" : "+v"(x)); }

static __device__ __forceinline__ uint  fu(float f) { return __float_as_uint(f); }
static __device__ __forceinline__ float uf(uint u)  { return __uint_as_float(u); }

static __device__ __forceinline__ ushort f2bf_rne(float f) {
    uint u = fu(f);
    u += 0x7fffu + ((u >> 16) & 1u);
    return (ushort)(u >> 16);
}
static __device__ __forceinline__ void split_rne(float f, ushort& hi, ushort& lo) {
    hi = f2bf_rne(f);
    float r = f - uf((uint)hi << 16);
    lo = f2bf_rne(r);
}

// conv2 row-permutation tap (verified r7-r13)
static __device__ __forceinline__ int tap_kk(int mtodd, int qr, int rr) {
    if (!mtodd) return 5 * qr + rr;
    if (rr == 0) return 5 * qr + 4;
    if (rr == 1) return 20 + qr;
    if (rr == 2 && qr == 3) return 24;
    return -1;
}

// conv1 K-slot -> original k (pair-packed scheme, verified r10-r13)
static __device__ __forceinline__ int slot_k(int q, int i) {
    const int p = 4 * q + (i >> 1), e = i & 1;
    if (p <= 8)  return e ? 9 + p : p;
    if (p <= 11) return 18 + 3 * (p - 9) + e;
    if (p <= 14) return e ? -1 : 18 + 3 * (p - 12) + 2;
    return -1;
}

// ===================== setup: per-lane MFMA params -> ws =====================
// chunks (uint4 ws[chunk*64 + lane]):
//  0..1 a1h[t]  2..3 a1l[t]   conv1 A, slot-mapped per slot_k, split hi/lo
//  4..7 a2[mt]                conv2 A (K-permuted oc), RNE bf16
// 12..13 bi1[t]  14..17 bi2[mt]
// 18 off1 int4               4 word-offsets into g32 (fb plane | w plane)
__global__ __launch_bounds__(64)
void setup_params(const float* __restrict__ w1, const float* __restrict__ b1,
                  const float* __restrict__ w2, const float* __restrict__ b2,
                  uint4v* __restrict__ ws)
{
    const int L = threadIdx.x;
    const int c = L & 15, q = L >> 4;

    #pragma unroll
    for (int t = 0; t < 2; ++t) {
        short8 hi8, lo8;
        #pragma unroll
        for (int i = 0; i < 8; ++i) {
            const int k = slot_k(q, i);
            const float f = (k >= 0) ? w1[(16 * t + c) * 27 + k] : 0.f;
            ushort h_, l_; split_rne(f, h_, l_);
            hi8[i] = (short)h_; lo8[i] = (short)l_;
        }
        *reinterpret_cast<short8*>(&ws[(0 + t) * 64 + L]) = hi8;
        *reinterpret_cast<short8*>(&ws[(2 + t) * 64 + L]) = lo8;
    }
    #pragma unroll
    for (int mt = 0; mt < 4; ++mt) {
        const int ch = mt >> 1;
        const int kk = tap_kk(mt & 1, c >> 2, c & 3);
        short8 a8;
        #pragma unroll
        for (int i = 0; i < 8; ++i) {
            const int oc = (i < 4) ? (4 * q + i) : (16 + 4 * q + (i - 4));
            const float f = (kk >= 0) ? w2[(25 * ch + kk) * 32 + oc] : 0.f;
            a8[i] = (short)f2bf_rne(f);
        }
        *reinterpret_cast<short8*>(&ws[(4 + mt) * 64 + L]) = a8;
    }
    #pragma unroll
    for (int t = 0; t < 2; ++t) {
        float4v v;
        #pragma unroll
        for (int r = 0; r < 4; ++r) v[r] = b1[16 * t + 4 * q + r];
        *reinterpret_cast<float4v*>(&ws[(12 + t) * 64 + L]) = v;
    }
    #pragma unroll
    for (int mt = 0; mt < 4; ++mt) {
        const int ch = mt >> 1;
        float4v v;
        #pragma unroll
        for (int r = 0; r < 4; ++r) {
            const int kk = tap_kk(mt & 1, q, r);
            v[r] = (kk >= 0) ? b2[25 * ch + kk] : 0.f;
        }
        *reinterpret_cast<float4v*>(&ws[(14 + mt) * 64 + L]) = v;
    }
    {
        int4v o;
        #pragma unroll
        for (int pl = 0; pl < 4; ++pl) {
            const int p = 4 * q + pl;
            int off;
            if (p <= 8)       off = (p / 3) * GS2 + (p % 3);        // FB word
            else if (p <= 11) off = FBWORDS + (p - 9) * GS2;        // W (ky,0)
            else if (p <= 14) off = FBWORDS + (p - 12) * GS2 + 2;   // W (ky,2)
            else              off = FBWORDS;                        // pad (dead)
            o[pl] = off;
        }
        *reinterpret_cast<int4v*>(&ws[18 * 64 + L]) = o;
    }
}

// ====== fused: guidance in staging + convs + combine ======
__global__ __launch_bounds__(256, 3)
void fused_kernel(const float* __restrict__ v0,
                  const float* __restrict__ v2,
                  const uint4v* __restrict__ P,
                  float* __restrict__ out)
{
    __shared__ uint    g32[2 * FBWORDS];          // fb-pair plane | w-pair plane
    __shared__ float2v f2[FR * FPS2];             // flow tile, channels interleaved

    const int bx0 = blockIdx.x * TSX;
    const int by0 = blockIdx.y * TSY;
    const int b   = blockIdx.z;
    const int tid = threadIdx.x;
    const int w   = tid >> 6;
    const int L   = tid & 63;
    const int c   = L & 15;
    const int q   = L >> 4;

    const float* v0b = v0 + (size_t)b * 2 * HW;
    const float* v2b = v2 + (size_t)b * 2 * HW;

    // ---- per-lane params (loaded once) ----
    short8 a1h[2], a1l[2], a2[4];
    #pragma unroll
    for (int t = 0; t < 2; ++t) {
        a1h[t] = *reinterpret_cast<const short8*>(&P[(0 + t) * 64 + L]); keep(a1h[t]);
        a1l[t] = *reinterpret_cast<const short8*>(&P[(2 + t) * 64 + L]); keep(a1l[t]);
    }
    #pragma unroll
    for (int mt = 0; mt < 4; ++mt) {
        a2[mt] = *reinterpret_cast<const short8*>(&P[(4 + mt) * 64 + L]); keep(a2[mt]);
    }
    float4v bi1[2], bi2[4];
    #pragma unroll
    for (int t = 0; t < 2; ++t) {
        bi1[t] = *reinterpret_cast<const float4v*>(&P[(12 + t) * 64 + L]); keep(bi1[t]);
    }
    #pragma unroll
    for (int mt = 0; mt < 4; ++mt) {
        bi2[mt] = *reinterpret_cast<const float4v*>(&P[(14 + mt) * 64 + L]); keep(bi2[mt]);
    }
    int off1[4];
    {
        int4v o = *reinterpret_cast<const int4v*>(&P[18 * 64 + L]); keep(o);
        #pragma unroll
        for (int pl = 0; pl < 4; ++pl) off1[pl] = o[pl];
    }

    // ---- stage flow tile (36x36, halo 2), channels interleaved ----
    for (int i = tid; i < FR * FR; i += 256) {
        const int ly = i / FR, lx = i - (i / FR) * FR;
        const int y = by0 - 2 + ly, x = bx0 - 2 + lx;
        float f0 = 0.f, f1 = 0.f;
        if ((unsigned)y < HH && (unsigned)x < WW) {
            f0 = v0b[y * WW + x];
            f1 = v0b[HW + y * WW + x];
        }
        float2v p; p[0] = f0; p[1] = f1;
        f2[ly * FPS2 + lx] = p;
    }

    // ---- stage guidance (34x34): compute fb/w in place ----
    // fb word: ds_write_b32. w: two ds_write_b16 building pair-packed words
    // (item (r,cc) fills word cc low half and word cc-1 high half).
    ushort* w16 = reinterpret_cast<ushort*>(g32 + FBWORDS);
    for (int i = tid; i < GR * GR; i += 256) {
        const int r = i / GR, cc = i - (i / GR) * GR;
        const int y = by0 - 1 + r, x = bx0 - 1 + cc;
        uint fbw = 0u;
        ushort wv16 = 0;
        if ((unsigned)y < HH && (unsigned)x < WW) {
            const float f0 = v0b[y * WW + x];
            const float f1 = v0b[HW + y * WW + x];
            const float sgx = (-1.0f + x * (2.0f / (WW - 1))) + f0 * (2.0f / WW);
            const float sgy = (-1.0f + y * (2.0f / (HH - 1))) + f1 * (2.0f / HH);
            const float ixf = (sgx + 1.0f) * (0.5f * (WW - 1));
            const float iyf = (sgy + 1.0f) * (0.5f * (HH - 1));
            const float x0f = floorf(ixf), y0f = floorf(iyf);
            const int   x0  = (int)x0f,   y0i = (int)y0f;
            const float wx1 = ixf - x0f, wx0 = 1.0f - wx1;
            const float wy1 = iyf - y0f, wy0 = 1.0f - wy1;
            float s0 = 0.f, s1 = 0.f;
            #pragma unroll
            for (int cy = 0; cy < 2; ++cy) {
                const int yc = y0i + cy;
                const float wy = cy ? wy1 : wy0;
                if (yc >= 0 && yc < HH) {
                    #pragma unroll
                    for (int cx = 0; cx < 2; ++cx) {
                        const int xc = x0 + cx;
                        if (xc >= 0 && xc < WW) {
                            const float wgt = wy * (cx ? wx1 : wx0);
                            const int i2 = yc * WW + xc;
                            s0 = fmaf(wgt, v2b[i2], s0);
                            s1 = fmaf(wgt, v2b[HW + i2], s1);
                        }
                    }
                }
            }
            const float fb0 = f0 + s0;
            const float fb1 = f1 + s1;
            const float wv  = __expf(-sqrtf(fmaf(fb0, fb0, fb1 * fb1)));
            fbw  = (uint)f2bf_rne(fb0) | ((uint)f2bf_rne(fb1) << 16);
            wv16 = f2bf_rne(wv);
        }
        g32[r * GS2 + cc] = fbw;
        const int rowb = r * (2 * GS2);
        w16[rowb + 2 * cc] = wv16;
        if (cc > 0)   w16[rowb + 2 * cc - 1] = wv16;   // high half of word cc-1
        if (cc == 33) w16[rowb + 67] = 0;              // dead element: keep finite
    }
    __syncthreads();

    // ---- 16 groups of 16 px per wave ----
    #pragma unroll 2
    for (int g = 0; g < 16; ++g) {
        const int py = 8 * w + (g >> 1);
        const int px = 16 * (g & 1) + c;
        const int gb = py * GS2 + px;

        // B1 frag: 4 u32 word gathers -> short8
        uint4v uw;
        #pragma unroll
        for (int pl = 0; pl < 4; ++pl) uw[pl] = g32[off1[pl] + gb];
        const short8 b1 = *reinterpret_cast<const short8*>(&uw);

        // conv3x3 GEMM (bf16 B, split A), bias in C
        float4v acc1_0 = bi1[0], acc1_1 = bi1[1];
        acc1_0 = MFMA16x32(a1l[0], b1, acc1_0);
        acc1_0 = MFMA16x32(a1h[0], b1, acc1_0);
        acc1_1 = MFMA16x32(a1l[1], b1, acc1_1);
        acc1_1 = MFMA16x32(a1h[1], b1, acc1_1);

        // ReLU + truncation bf16 (hi only; headroom verified) -> conv2 B frag
        short8 b2h;
        #pragma unroll
        for (int r = 0; r < 4; ++r) {
            const float h0 = fmaxf(acc1_0[r], 0.f);
            const float h1 = fmaxf(acc1_1[r], 0.f);
            b2h[r]     = (short)(fu(h0) >> 16);
            b2h[4 + r] = (short)(fu(h1) >> 16);
        }

        // conv1x1 GEMM via K-permuted 16x16x32, hi term only (4 MFMA)
        float4v acc2[4] = {bi2[0], bi2[1], bi2[2], bi2[3]};
        #pragma unroll
        for (int mt = 0; mt < 4; ++mt)
            acc2[mt] = MFMA16x32(a2[mt], b2h, acc2[mt]);

        // combine: 7 x ds_read_b64 (both channels per read)
        const int pyb   = py * FPS2 + px;
        const int base0 = pyb + q * FPS2;         // taps (q, 0..4)
        const int b4    = pyb + 4 * FPS2 + q;     // tap  (4, q)

        const float2v p0 = f2[base0];
        const float2v p1 = f2[base0 + 1];
        const float2v p2 = f2[base0 + 2];
        const float2v p3 = f2[base0 + 3];
        const float2v p4 = f2[base0 + 4];
        const float2v pb = f2[b4];
        const float2v pc = f2[base0 + 41];        // (4,4): kern==0 unless q==3

        float s0 = 0.f, s1 = 0.f;
        s0 = fmaf(acc2[0][0], p0[0], s0);  s1 = fmaf(acc2[2][0], p0[1], s1);
        s0 = fmaf(acc2[0][1], p1[0], s0);  s1 = fmaf(acc2[2][1], p1[1], s1);
        s0 = fmaf(acc2[0][2], p2[0], s0);  s1 = fmaf(acc2[2][2], p2[1], s1);
        s0 = fmaf(acc2[0][3], p3[0], s0);  s1 = fmaf(acc2[2][3], p3[1], s1);
        s0 = fmaf(acc2[1][0], p4[0], s0);  s1 = fmaf(acc2[3][0], p4[1], s1);
        s0 = fmaf(acc2[1][1], pb[0], s0);  s1 = fmaf(acc2[3][1], pb[1], s1);
        s0 = fmaf(acc2[1][2], pc[0], s0);  s1 = fmaf(acc2[3][2], pc[1], s1);

        s0 += __shfl_xor(s0, 16);
        s0 += __shfl_xor(s0, 32);
        s1 += __shfl_xor(s1, 16);
        s1 += __shfl_xor(s1, 32);

        if (q == 0) {
            const int y = by0 + py, x = bx0 + px;
            out[((size_t)b * 2 + 0) * HW + y * WW + x] = s0;
            out[((size_t)b * 2 + 1) * HW + y * WW + x] = s1;
        }
    }
}

extern "C" void kernel_launch(void* const* d_in, const int* in_sizes, int n_in,
                              void* d_out, int out_size, void* d_ws, size_t ws_size,
                              hipStream_t stream) {
    const float* v0 = (const float*)d_in[0];
    const float* v2 = (const float*)d_in[1];
    const float* w1 = (const float*)d_in[2];
    const float* b1 = (const float*)d_in[3];
    const float* w2 = (const float*)d_in[4];
    const float* b2 = (const float*)d_in[5];
    uint4v* ws = (uint4v*)d_ws;

    setup_params<<<1, 64, 0, stream>>>(w1, b1, w2, b2, ws);

    dim3 grid(WW / TSX, HH / TSY, BB);
    fused_kernel<<<grid, dim3(256, 1, 1), 0, stream>>>(v0, v2, ws, (float*)d_out);
}